// Round 2
// baseline (437.383 us; speedup 1.0000x reference)
//
#include <hip/hip_runtime.h>

#define NBATCH 32
#define NH 16
#define NT 16
#define DD 64
#define SS 1024
#define LL 1024
#define TOTK 2064
#define EE 1024
#define NSPLIT 4

typedef __attribute__((ext_vector_type(8))) short bf16x8;
typedef __attribute__((ext_vector_type(4))) float f32x4;

__device__ __forceinline__ unsigned short f2bf(float x) {
  union { float f; unsigned u; } v; v.f = x;
  unsigned r = v.u + 0x7fffu + ((v.u >> 16) & 1u);
  return (unsigned short)(r >> 16);
}

// ---------------- QKV projection ----------------
// grid (8 mtiles, 48 ntiles), 256 threads (4 waves). ntile -> (mat, h).
// 64x64 tile, BK=64, register-prefetch double buffering.
__global__ __launch_bounds__(256)
void proj_kernel(const float* __restrict__ hidden,
                 const float* __restrict__ Wq, const float* __restrict__ bq,
                 const float* __restrict__ Wk, const float* __restrict__ bk,
                 const float* __restrict__ Wv, const float* __restrict__ bv,
                 unsigned short* __restrict__ qws,
                 float* __restrict__ kws, float* __restrict__ vws)
{
  __shared__ alignas(16) unsigned short As[64][72];  // rows 144B (16B mult)
  __shared__ alignas(16) unsigned short Bs[64][72];
  const int mtile = blockIdx.x;
  const int ntile = blockIdx.y;
  const int mat = ntile >> 4;
  const int h = ntile & 15;
  const float* Wm = (mat == 0) ? Wq : (mat == 1 ? Wk : Wv);
  const float* bm = (mat == 0) ? bq : (mat == 1 ? bk : bv);
  const int tid = threadIdx.x;
  const int lane = tid & 63, w = tid >> 6;
  const int lr = lane & 15, lg = lane >> 4;
  const int m0 = mtile * 64;

  const f32x4 fz = {0.f, 0.f, 0.f, 0.f};
  f32x4 acc[4];
  #pragma unroll
  for (int j = 0; j < 4; ++j) acc[j] = fz;

  const int srow = tid >> 4, sc4 = tid & 15;   // each thread: 4 rows stride 16
  float4 Ar[4], Br[4];
  #pragma unroll
  for (int it = 0; it < 4; ++it) {
    Ar[it] = *(const float4*)(hidden + (m0 + srow + it * 16) * EE + sc4 * 4);
    Br[it] = *(const float4*)(Wm + (h * 64 + srow + it * 16) * EE + sc4 * 4);
  }

  for (int k0 = 0; k0 < EE; k0 += 64) {
    __syncthreads();
    #pragma unroll
    for (int it = 0; it < 4; ++it) {
      int row = srow + it * 16;
      float4 a = Ar[it], b = Br[it];
      *(ushort4*)(&As[row][sc4 * 4]) = make_ushort4(f2bf(a.x), f2bf(a.y), f2bf(a.z), f2bf(a.w));
      *(ushort4*)(&Bs[row][sc4 * 4]) = make_ushort4(f2bf(b.x), f2bf(b.y), f2bf(b.z), f2bf(b.w));
    }
    __syncthreads();
    int kn = k0 + 64;
    if (kn < EE) {
      #pragma unroll
      for (int it = 0; it < 4; ++it) {
        Ar[it] = *(const float4*)(hidden + (m0 + srow + it * 16) * EE + kn + sc4 * 4);
        Br[it] = *(const float4*)(Wm + (h * 64 + srow + it * 16) * EE + kn + sc4 * 4);
      }
    }
    #pragma unroll
    for (int hh = 0; hh < 2; ++hh) {
      bf16x8 a = *(const bf16x8*)(&As[w * 16 + lr][hh * 32 + lg * 8]);
      #pragma unroll
      for (int dt = 0; dt < 4; ++dt) {
        bf16x8 b = *(const bf16x8*)(&Bs[dt * 16 + lr][hh * 32 + lg * 8]);
        acc[dt] = __builtin_amdgcn_mfma_f32_16x16x32_bf16(a, b, acc[dt], 0, 0, 0);
      }
    }
  }

  // epilogue: C/D map col=lane&15, row=(lane>>4)*4+reg
  #pragma unroll
  for (int dt = 0; dt < 4; ++dt)
    #pragma unroll
    for (int r = 0; r < 4; ++r) {
      int Mrow = m0 + w * 16 + lg * 4 + r;
      int nb = Mrow >> 4, t = Mrow & 15;
      int d = dt * 16 + lr;
      float val = acc[dt][r] + bm[h * 64 + d];
      int oi = ((nb * NH + h) * NT + t) * DD + d;
      if (mat == 0) qws[oi] = f2bf(val);
      else if (mat == 1) kws[oi] = val;
      else vws[oi] = val;
    }
}

// ---------------- fused prefix attention, split-K, direct-frag loads ----------------
struct TileLd { float4 kf[8]; float vf[32]; float rf[8]; };

__device__ __forceinline__ void tile_src(int tt, int nb, int n, int h,
                                         const float* ppk, const float* ppv,
                                         const float* pk, const float* pv,
                                         const float* kws, const float* vws,
                                         const float*& ksrc, const float*& vsrc,
                                         int& jabs0, int& valid)
{
  if (tt < 32) {
    int j = tt * 32;
    ksrc = ppk + ((n * NH + h) * SS + j) * DD;
    vsrc = ppv + ((n * NH + h) * SS + j) * DD;
    jabs0 = j; valid = 32;
  } else if (tt < 64) {
    int j = (tt - 32) * 32;
    ksrc = pk + ((nb * NH + h) * LL + j) * DD;
    vsrc = pv + ((nb * NH + h) * LL + j) * DD;
    jabs0 = SS + j; valid = 32;
  } else {
    ksrc = kws + ((nb * NH + h) * NT) * DD;
    vsrc = vws + ((nb * NH + h) * NT) * DD;
    jabs0 = SS + LL; valid = 16;
  }
}

__device__ __forceinline__ void load_tile(const float* __restrict__ ksrc,
                                          const float* __restrict__ vsrc,
                                          const float* __restrict__ relbase,
                                          int jabs0, int valid, int lr, int lg,
                                          TileLd& T)
{
  const float4 z4 = {0.f, 0.f, 0.f, 0.f};
  #pragma unroll
  for (int sub = 0; sub < 2; ++sub) {
    int row = sub * 16 + lr;
    bool ok = row < valid;
    #pragma unroll
    for (int hh = 0; hh < 2; ++hh)
      #pragma unroll
      for (int q = 0; q < 2; ++q)
        T.kf[(sub * 2 + hh) * 2 + q] =
            ok ? *(const float4*)(ksrc + row * DD + hh * 32 + lg * 8 + q * 4) : z4;
  }
  #pragma unroll
  for (int dt = 0; dt < 4; ++dt)
    #pragma unroll
    for (int e = 0; e < 8; ++e) {
      int j = lg * 8 + e;
      T.vf[dt * 8 + e] = (j < valid) ? vsrc[j * DD + dt * 16 + lr] : 0.f;
    }
  #pragma unroll
  for (int sub = 0; sub < 2; ++sub)
    #pragma unroll
    for (int r = 0; r < 4; ++r) {
      int jloc = sub * 16 + lr;
      int t = lg * 4 + r;
      T.rf[sub * 4 + r] = (jloc < valid) ? relbase[t * TOTK + jabs0 + jloc] : 0.f;
    }
}

__device__ __forceinline__ void conv_tile(const TileLd& T, bf16x8 kb[4], bf16x8 vb[4],
                                          float rc[8])
{
  #pragma unroll
  for (int f = 0; f < 4; ++f) {
    bf16x8 o;
    #pragma unroll
    for (int q = 0; q < 2; ++q) {
      float4 v = T.kf[f * 2 + q];
      o[q * 4 + 0] = (short)f2bf(v.x); o[q * 4 + 1] = (short)f2bf(v.y);
      o[q * 4 + 2] = (short)f2bf(v.z); o[q * 4 + 3] = (short)f2bf(v.w);
    }
    kb[f] = o;
  }
  #pragma unroll
  for (int dt = 0; dt < 4; ++dt) {
    bf16x8 o;
    #pragma unroll
    for (int e = 0; e < 8; ++e) o[e] = (short)f2bf(T.vf[dt * 8 + e]);
    vb[dt] = o;
  }
  #pragma unroll
  for (int i = 0; i < 8; ++i) rc[i] = T.rf[i];
}

__global__ __launch_bounds__(256, 3)
void attn_kernel(const float* __restrict__ mask, const float* __restrict__ rel,
                 const float* __restrict__ ppk, const float* __restrict__ ppv,
                 const float* __restrict__ pk, const float* __restrict__ pv,
                 const unsigned short* __restrict__ qws,
                 const float* __restrict__ kws, const float* __restrict__ vws,
                 float* __restrict__ pctx, float* __restrict__ pml)
{
  __shared__ alignas(16) unsigned short Pb[4][16][40];
  __shared__ float mgc[4][16][64];
  __shared__ float mgml[4][16][2];

  const int wg = blockIdx.x;          // 512 = nb*16 + h
  const int split = blockIdx.y;       // 0..3
  const int nb = wg >> 4, h = wg & 15;
  const int n = nb >> 2;
  const int tid = threadIdx.x;
  const int lane = tid & 63, w = tid >> 6;
  const int lr = lane & 15, lg = lane >> 4;

  const unsigned short* qbase = qws + ((nb * NH + h) * NT) * DD;
  bf16x8 aq0 = *(const bf16x8*)(qbase + lr * DD + lg * 8);
  bf16x8 aq1 = *(const bf16x8*)(qbase + lr * DD + lg * 8 + 32);

  const float* relbase = rel + ((nb * NH + h) * NT) * TOTK;
  const float* mbase = mask + nb * TOTK;

  float m_r[4], l_r[4];
  const f32x4 fz = {0.f, 0.f, 0.f, 0.f};
  f32x4 ctx[4];
  #pragma unroll
  for (int r = 0; r < 4; ++r) { m_r[r] = -1e30f; l_r[r] = 0.f; }
  #pragma unroll
  for (int dt = 0; dt < 4; ++dt) ctx[dt] = fz;

  const int base = split * 16;
  const int tend = base + ((split == NSPLIT - 1) ? 17 : 16);

  // prologue: load + convert first tile
  int tt = base + w;
  const float *ksrc, *vsrc; int cj, cv;
  tile_src(tt, nb, n, h, ppk, ppv, pk, pv, kws, vws, ksrc, vsrc, cj, cv);
  TileLd T;
  load_tile(ksrc, vsrc, relbase, cj, cv, lr, lg, T);
  bf16x8 kb[4], vb[4]; float rc[8];
  conv_tile(T, kb, vb, rc);

  int ttn = tt + 4;
  while (true) {
    bool hn = ttn < tend;
    int nj = 0, nv = 0;
    if (hn) {  // issue prefetch (latency hidden under compute below)
      tile_src(ttn, nb, n, h, ppk, ppv, pk, pv, kws, vws, ksrc, vsrc, nj, nv);
      load_tile(ksrc, vsrc, relbase, nj, nv, lr, lg, T);
    }

    // ---- compute current tile from kb/vb/rc ----
    float sc[2][4];
    #pragma unroll
    for (int sub = 0; sub < 2; ++sub) {
      f32x4 s = fz;
      s = __builtin_amdgcn_mfma_f32_16x16x32_bf16(aq0, kb[sub * 2 + 0], s, 0, 0, 0);
      s = __builtin_amdgcn_mfma_f32_16x16x32_bf16(aq1, kb[sub * 2 + 1], s, 0, 0, 0);
      int jloc = sub * 16 + lr;
      int jabs = cj + jloc;
      bool jok = jloc < cv;
      float mval = jok ? mbase[jabs] : 0.f;
      #pragma unroll
      for (int r = 0; r < 4; ++r)
        sc[sub][r] = jok ? (s[r] * 0.125f + rc[sub * 4 + r] + mval) : -1e30f;
    }

    #pragma unroll
    for (int r = 0; r < 4; ++r) {
      float tmax = fmaxf(sc[0][r], sc[1][r]);
      #pragma unroll
      for (int o = 8; o >= 1; o >>= 1) tmax = fmaxf(tmax, __shfl_xor(tmax, o, 16));
      float mnew = fmaxf(m_r[r], tmax);
      float alpha = __expf(m_r[r] - mnew);
      float p0 = __expf(sc[0][r] - mnew);
      float p1 = __expf(sc[1][r] - mnew);
      float rs = p0 + p1;
      #pragma unroll
      for (int o = 8; o >= 1; o >>= 1) rs += __shfl_xor(rs, o, 16);
      l_r[r] = l_r[r] * alpha + rs;
      m_r[r] = mnew;
      #pragma unroll
      for (int dt = 0; dt < 4; ++dt) ctx[dt][r] *= alpha;
      int t = lg * 4 + r;
      Pb[w][t][lr] = f2bf(p0);
      Pb[w][t][16 + lr] = f2bf(p1);
    }

    bf16x8 pa = *(const bf16x8*)(&Pb[w][lr][lg * 8]);
    #pragma unroll
    for (int dt = 0; dt < 4; ++dt)
      ctx[dt] = __builtin_amdgcn_mfma_f32_16x16x32_bf16(pa, vb[dt], ctx[dt], 0, 0, 0);
    // ---- end compute ----

    if (!hn) break;
    conv_tile(T, kb, vb, rc);   // waits on prefetch loads (latency already hidden)
    cj = nj; cv = nv;
    ttn += 4;
  }

  // block-level merge of 4 waves -> unnormalized partial (M, L, CTX)
  __syncthreads();
  #pragma unroll
  for (int dt = 0; dt < 4; ++dt)
    #pragma unroll
    for (int r = 0; r < 4; ++r)
      mgc[w][lg * 4 + r][dt * 16 + lr] = ctx[dt][r];
  if (lr == 0) {
    #pragma unroll
    for (int r = 0; r < 4; ++r) {
      mgml[w][lg * 4 + r][0] = m_r[r];
      mgml[w][lg * 4 + r][1] = l_r[r];
    }
  }
  __syncthreads();
  const int pidx = wg * NSPLIT + split;
  #pragma unroll
  for (int i = 0; i < 4; ++i) {
    int idx = i * 256 + tid;
    int t = idx >> 6, d = idx & 63;
    float M = -1e30f;
    #pragma unroll
    for (int ww = 0; ww < 4; ++ww) M = fmaxf(M, mgml[ww][t][0]);
    float num = 0.f, den = 0.f;
    #pragma unroll
    for (int ww = 0; ww < 4; ++ww) {
      float e = __expf(mgml[ww][t][0] - M);
      den += mgml[ww][t][1] * e;
      num += mgc[ww][t][d] * e;
    }
    pctx[(pidx * 16 + t) * 64 + d] = num;
    if (d == 0) {
      pml[(pidx * 16 + t) * 2 + 0] = M;
      pml[(pidx * 16 + t) * 2 + 1] = den;
    }
  }
}

// ---------------- split merge ----------------
__global__ __launch_bounds__(256)
void merge_kernel(const float* __restrict__ pctx, const float* __restrict__ pml,
                  float* __restrict__ out)
{
  const int wg = blockIdx.x;   // (nb,h)
  const int nb = wg >> 4, h = wg & 15;
  const int tid = threadIdx.x;
  #pragma unroll
  for (int i = 0; i < 4; ++i) {
    int idx = i * 256 + tid;
    int t = idx >> 6, d = idx & 63;
    float M = -1e30f;
    #pragma unroll
    for (int s = 0; s < NSPLIT; ++s)
      M = fmaxf(M, pml[((wg * NSPLIT + s) * 16 + t) * 2 + 0]);
    float num = 0.f, den = 0.f;
    #pragma unroll
    for (int s = 0; s < NSPLIT; ++s) {
      float e = __expf(pml[((wg * NSPLIT + s) * 16 + t) * 2 + 0] - M);
      den += pml[((wg * NSPLIT + s) * 16 + t) * 2 + 1] * e;
      num += pctx[((wg * NSPLIT + s) * 16 + t) * 64 + d] * e;
    }
    out[((nb * NT + t) * NH + h) * DD + d] = num / den;
  }
}

extern "C" void kernel_launch(void* const* d_in, const int* in_sizes, int n_in,
                              void* d_out, int out_size, void* d_ws, size_t ws_size,
                              hipStream_t stream) {
  const float* hidden = (const float*)d_in[0];
  const float* mask   = (const float*)d_in[1];
  const float* rel    = (const float*)d_in[2];
  const float* ppk    = (const float*)d_in[3];
  const float* ppv    = (const float*)d_in[4];
  const float* pk     = (const float*)d_in[5];
  const float* pv     = (const float*)d_in[6];
  const float* Wq     = (const float*)d_in[7];
  const float* bq     = (const float*)d_in[8];
  const float* Wk     = (const float*)d_in[9];
  const float* bk     = (const float*)d_in[10];
  const float* Wv     = (const float*)d_in[11];
  const float* bv     = (const float*)d_in[12];
  float* out = (float*)d_out;

  unsigned short* qws = (unsigned short*)d_ws;                 // 1 MB bf16 Q
  float* kws = (float*)((char*)d_ws + (1u << 20));             // 2 MB fp32 new K
  float* vws = (float*)((char*)d_ws + 3u * (1u << 20));        // 2 MB fp32 new V
  float* pctx = (float*)((char*)d_ws + 5u * (1u << 20));       // 8 MB partial ctx
  float* pml  = (float*)((char*)d_ws + 13u * (1u << 20));      // 256 KB partial m/l

  proj_kernel<<<dim3(8, 48), 256, 0, stream>>>(hidden, Wq, bq, Wk, bk, Wv, bv,
                                               qws, kws, vws);
  attn_kernel<<<dim3(512, NSPLIT), 256, 0, stream>>>(mask, rel, ppk, ppv, pk, pv,
                                                     qws, kws, vws, pctx, pml);
  merge_kernel<<<dim3(512), 256, 0, stream>>>(pctx, pml, out);
}

// Round 3
// 151.998 us; speedup vs baseline: 2.8776x; 2.8776x over previous
//
#include <hip/hip_runtime.h>

#define NBATCH 32
#define NH 16
#define NT 16
#define DD 64
#define SS 1024
#define LL 1024
#define TOTK 2064
#define EE 1024
#define NSPLIT 4

typedef __attribute__((ext_vector_type(8))) short bf16x8;
typedef __attribute__((ext_vector_type(4))) float f32x4;

__device__ __forceinline__ unsigned short f2bf(float x) {
  union { float f; unsigned u; } v; v.f = x;
  unsigned r = v.u + 0x7fffu + ((v.u >> 16) & 1u);
  return (unsigned short)(r >> 16);
}

// ---------------- QKV projection ----------------
// grid (8 mtiles, 48 ntiles), 256 threads (4 waves). 64x64 tile, BK=64,
// register-prefetch double buffering (validated round 2).
__global__ __launch_bounds__(256)
void proj_kernel(const float* __restrict__ hidden,
                 const float* __restrict__ Wq, const float* __restrict__ bq,
                 const float* __restrict__ Wk, const float* __restrict__ bk,
                 const float* __restrict__ Wv, const float* __restrict__ bv,
                 unsigned short* __restrict__ qws,
                 float* __restrict__ kws, float* __restrict__ vws)
{
  __shared__ alignas(16) unsigned short As[64][72];
  __shared__ alignas(16) unsigned short Bs[64][72];
  const int mtile = blockIdx.x;
  const int ntile = blockIdx.y;
  const int mat = ntile >> 4;
  const int h = ntile & 15;
  const float* Wm = (mat == 0) ? Wq : (mat == 1 ? Wk : Wv);
  const float* bm = (mat == 0) ? bq : (mat == 1 ? bk : bv);
  const int tid = threadIdx.x;
  const int lane = tid & 63, w = tid >> 6;
  const int lr = lane & 15, lg = lane >> 4;
  const int m0 = mtile * 64;

  const f32x4 fz = {0.f, 0.f, 0.f, 0.f};
  f32x4 acc[4];
  #pragma unroll
  for (int j = 0; j < 4; ++j) acc[j] = fz;

  const int srow = tid >> 4, sc4 = tid & 15;
  float4 Ar[4], Br[4];
  #pragma unroll
  for (int it = 0; it < 4; ++it) {
    Ar[it] = *(const float4*)(hidden + (m0 + srow + it * 16) * EE + sc4 * 4);
    Br[it] = *(const float4*)(Wm + (h * 64 + srow + it * 16) * EE + sc4 * 4);
  }

  for (int k0 = 0; k0 < EE; k0 += 64) {
    __syncthreads();
    #pragma unroll
    for (int it = 0; it < 4; ++it) {
      int row = srow + it * 16;
      float4 a = Ar[it], b = Br[it];
      *(ushort4*)(&As[row][sc4 * 4]) = make_ushort4(f2bf(a.x), f2bf(a.y), f2bf(a.z), f2bf(a.w));
      *(ushort4*)(&Bs[row][sc4 * 4]) = make_ushort4(f2bf(b.x), f2bf(b.y), f2bf(b.z), f2bf(b.w));
    }
    __syncthreads();
    int kn = k0 + 64;
    if (kn < EE) {
      #pragma unroll
      for (int it = 0; it < 4; ++it) {
        Ar[it] = *(const float4*)(hidden + (m0 + srow + it * 16) * EE + kn + sc4 * 4);
        Br[it] = *(const float4*)(Wm + (h * 64 + srow + it * 16) * EE + kn + sc4 * 4);
      }
    }
    #pragma unroll
    for (int hh = 0; hh < 2; ++hh) {
      bf16x8 a = *(const bf16x8*)(&As[w * 16 + lr][hh * 32 + lg * 8]);
      #pragma unroll
      for (int dt = 0; dt < 4; ++dt) {
        bf16x8 b = *(const bf16x8*)(&Bs[dt * 16 + lr][hh * 32 + lg * 8]);
        acc[dt] = __builtin_amdgcn_mfma_f32_16x16x32_bf16(a, b, acc[dt], 0, 0, 0);
      }
    }
  }

  #pragma unroll
  for (int dt = 0; dt < 4; ++dt)
    #pragma unroll
    for (int r = 0; r < 4; ++r) {
      int Mrow = m0 + w * 16 + lg * 4 + r;
      int nb = Mrow >> 4, t = Mrow & 15;
      int d = dt * 16 + lr;
      float val = acc[dt][r] + bm[h * 64 + d];
      int oi = ((nb * NH + h) * NT + t) * DD + d;
      if (mat == 0) qws[oi] = f2bf(val);
      else if (mat == 1) kws[oi] = val;
      else vws[oi] = val;
    }
}

// ---------------- fused prefix attention, split-K, direct-frag register loads ----------------
__device__ __forceinline__ void tile_src(int tt, int nb, int n, int h,
                                         const float* ppk, const float* ppv,
                                         const float* pk, const float* pv,
                                         const float* kws, const float* vws,
                                         const float*& ksrc, const float*& vsrc,
                                         int& jabs0, int& valid)
{
  if (tt < 32) {
    int j = tt * 32;
    ksrc = ppk + ((n * NH + h) * SS + j) * DD;
    vsrc = ppv + ((n * NH + h) * SS + j) * DD;
    jabs0 = j; valid = 32;
  } else if (tt < 64) {
    int j = (tt - 32) * 32;
    ksrc = pk + ((nb * NH + h) * LL + j) * DD;
    vsrc = pv + ((nb * NH + h) * LL + j) * DD;
    jabs0 = SS + j; valid = 32;
  } else {
    ksrc = kws + ((nb * NH + h) * NT) * DD;
    vsrc = vws + ((nb * NH + h) * NT) * DD;
    jabs0 = SS + LL; valid = 16;
  }
}

__global__ __launch_bounds__(256, 3)
void attn_kernel(const float* __restrict__ mask, const float* __restrict__ rel,
                 const float* __restrict__ ppk, const float* __restrict__ ppv,
                 const float* __restrict__ pk, const float* __restrict__ pv,
                 const unsigned short* __restrict__ qws,
                 const float* __restrict__ kws, const float* __restrict__ vws,
                 float* __restrict__ pctx, float* __restrict__ pml)
{
  __shared__ alignas(16) unsigned short Pb[4][16][40];
  __shared__ float mgc[4][16][64];
  __shared__ float mgml[4][16][2];

  const int wg = blockIdx.x;          // 512 = nb*16 + h
  const int split = blockIdx.y;       // 0..NSPLIT-1
  const int nb = wg >> 4, h = wg & 15;
  const int n = nb >> 2;
  const int tid = threadIdx.x;
  const int lane = tid & 63, w = tid >> 6;
  const int lr = lane & 15, lg = lane >> 4;

  const unsigned short* qbase = qws + ((nb * NH + h) * NT) * DD;
  bf16x8 aq0 = *(const bf16x8*)(qbase + lr * DD + lg * 8);
  bf16x8 aq1 = *(const bf16x8*)(qbase + lr * DD + lg * 8 + 32);

  const float* relbase = rel + ((nb * NH + h) * NT) * TOTK;
  const float* mbase = mask + nb * TOTK;

  float m_r[4], l_r[4];
  const f32x4 fz = {0.f, 0.f, 0.f, 0.f};
  f32x4 ctx[4];
  #pragma unroll
  for (int r = 0; r < 4; ++r) { m_r[r] = -1e30f; l_r[r] = 0.f; }
  #pragma unroll
  for (int dt = 0; dt < 4; ++dt) ctx[dt] = fz;

  const int base = split * 16;
  const int tend = base + ((split == NSPLIT - 1) ? 17 : 16);

  for (int tt = base + w; tt < tend; tt += 4) {
    const float *ksrc, *vsrc; int jabs0, valid;
    tile_src(tt, nb, n, h, ppk, ppv, pk, pv, kws, vws, ksrc, vsrc, jabs0, valid);

    // ---- issue ALL tile loads up front (stay in flight under QK^T+softmax) ----
    const float4 z4 = {0.f, 0.f, 0.f, 0.f};
    float4 kraw[8];
    #pragma unroll
    for (int sub = 0; sub < 2; ++sub) {
      int row = sub * 16 + lr;
      bool ok = row < valid;
      #pragma unroll
      for (int hh = 0; hh < 2; ++hh)
        #pragma unroll
        for (int q = 0; q < 2; ++q)
          kraw[(sub * 2 + hh) * 2 + q] =
              ok ? *(const float4*)(ksrc + row * DD + hh * 32 + lg * 8 + q * 4) : z4;
    }
    float vraw[32];
    #pragma unroll
    for (int dt = 0; dt < 4; ++dt)
      #pragma unroll
      for (int e = 0; e < 8; ++e) {
        int j = lg * 8 + e;
        vraw[dt * 8 + e] = (j < valid) ? vsrc[j * DD + dt * 16 + lr] : 0.f;
      }
    float rraw[8];
    #pragma unroll
    for (int sub = 0; sub < 2; ++sub)
      #pragma unroll
      for (int r = 0; r < 4; ++r) {
        int jloc = sub * 16 + lr;
        int t = lg * 4 + r;
        rraw[sub * 4 + r] = (jloc < valid) ? relbase[t * TOTK + jabs0 + jloc] : 0.f;
      }
    float mv[2];
    #pragma unroll
    for (int sub = 0; sub < 2; ++sub) {
      int jloc = sub * 16 + lr;
      mv[sub] = (jloc < valid) ? mbase[jabs0 + jloc] : 0.f;
    }

    // ---- convert K, QK^T ----
    bf16x8 kb[4];
    #pragma unroll
    for (int f = 0; f < 4; ++f) {
      bf16x8 o;
      #pragma unroll
      for (int q = 0; q < 2; ++q) {
        float4 v = kraw[f * 2 + q];
        o[q * 4 + 0] = (short)f2bf(v.x); o[q * 4 + 1] = (short)f2bf(v.y);
        o[q * 4 + 2] = (short)f2bf(v.z); o[q * 4 + 3] = (short)f2bf(v.w);
      }
      kb[f] = o;
    }
    float sc[2][4];
    #pragma unroll
    for (int sub = 0; sub < 2; ++sub) {
      f32x4 s = fz;
      s = __builtin_amdgcn_mfma_f32_16x16x32_bf16(aq0, kb[sub * 2 + 0], s, 0, 0, 0);
      s = __builtin_amdgcn_mfma_f32_16x16x32_bf16(aq1, kb[sub * 2 + 1], s, 0, 0, 0);
      bool jok = (sub * 16 + lr) < valid;
      #pragma unroll
      for (int r = 0; r < 4; ++r)
        sc[sub][r] = jok ? (s[r] * 0.125f + rraw[sub * 4 + r] + mv[sub]) : -1e30f;
    }

    // ---- online softmax (V loads still in flight) ----
    #pragma unroll
    for (int r = 0; r < 4; ++r) {
      float tmax = fmaxf(sc[0][r], sc[1][r]);
      #pragma unroll
      for (int o = 8; o >= 1; o >>= 1) tmax = fmaxf(tmax, __shfl_xor(tmax, o, 16));
      float mnew = fmaxf(m_r[r], tmax);
      float alpha = __expf(m_r[r] - mnew);
      float p0 = __expf(sc[0][r] - mnew);
      float p1 = __expf(sc[1][r] - mnew);
      float rs = p0 + p1;
      #pragma unroll
      for (int o = 8; o >= 1; o >>= 1) rs += __shfl_xor(rs, o, 16);
      l_r[r] = l_r[r] * alpha + rs;
      m_r[r] = mnew;
      #pragma unroll
      for (int dt = 0; dt < 4; ++dt) ctx[dt][r] *= alpha;
      int t = lg * 4 + r;
      Pb[w][t][lr] = f2bf(p0);
      Pb[w][t][16 + lr] = f2bf(p1);
    }

    // ---- convert V, PV ----
    bf16x8 pa = *(const bf16x8*)(&Pb[w][lr][lg * 8]);
    #pragma unroll
    for (int dt = 0; dt < 4; ++dt) {
      bf16x8 vb;
      #pragma unroll
      for (int e = 0; e < 8; ++e) vb[e] = (short)f2bf(vraw[dt * 8 + e]);
      ctx[dt] = __builtin_amdgcn_mfma_f32_16x16x32_bf16(pa, vb, ctx[dt], 0, 0, 0);
    }
  }

  // ---- block-level merge of 4 waves -> unnormalized partial (M, L, CTX) ----
  __syncthreads();
  #pragma unroll
  for (int dt = 0; dt < 4; ++dt)
    #pragma unroll
    for (int r = 0; r < 4; ++r)
      mgc[w][lg * 4 + r][dt * 16 + lr] = ctx[dt][r];
  if (lr == 0) {
    #pragma unroll
    for (int r = 0; r < 4; ++r) {
      mgml[w][lg * 4 + r][0] = m_r[r];
      mgml[w][lg * 4 + r][1] = l_r[r];
    }
  }
  __syncthreads();
  const int pidx = wg * NSPLIT + split;
  #pragma unroll
  for (int i = 0; i < 4; ++i) {
    int idx = i * 256 + tid;
    int t = idx >> 6, d = idx & 63;
    float M = -1e30f;
    #pragma unroll
    for (int ww = 0; ww < 4; ++ww) M = fmaxf(M, mgml[ww][t][0]);
    float num = 0.f, den = 0.f;
    #pragma unroll
    for (int ww = 0; ww < 4; ++ww) {
      float e = __expf(mgml[ww][t][0] - M);
      den += mgml[ww][t][1] * e;
      num += mgc[ww][t][d] * e;
    }
    pctx[(pidx * 16 + t) * 64 + d] = num;
    if (d == 0) {
      pml[(pidx * 16 + t) * 2 + 0] = M;
      pml[(pidx * 16 + t) * 2 + 1] = den;
    }
  }
}

// ---------------- split merge ----------------
__global__ __launch_bounds__(256)
void merge_kernel(const float* __restrict__ pctx, const float* __restrict__ pml,
                  float* __restrict__ out)
{
  const int wg = blockIdx.x;   // (nb,h)
  const int nb = wg >> 4, h = wg & 15;
  const int tid = threadIdx.x;
  #pragma unroll
  for (int i = 0; i < 4; ++i) {
    int idx = i * 256 + tid;
    int t = idx >> 6, d = idx & 63;
    float M = -1e30f;
    #pragma unroll
    for (int s = 0; s < NSPLIT; ++s)
      M = fmaxf(M, pml[((wg * NSPLIT + s) * 16 + t) * 2 + 0]);
    float num = 0.f, den = 0.f;
    #pragma unroll
    for (int s = 0; s < NSPLIT; ++s) {
      float e = __expf(pml[((wg * NSPLIT + s) * 16 + t) * 2 + 0] - M);
      den += pml[((wg * NSPLIT + s) * 16 + t) * 2 + 1] * e;
      num += pctx[((wg * NSPLIT + s) * 16 + t) * 64 + d] * e;
    }
    out[((nb * NT + t) * NH + h) * DD + d] = num / den;
  }
}

extern "C" void kernel_launch(void* const* d_in, const int* in_sizes, int n_in,
                              void* d_out, int out_size, void* d_ws, size_t ws_size,
                              hipStream_t stream) {
  const float* hidden = (const float*)d_in[0];
  const float* mask   = (const float*)d_in[1];
  const float* rel    = (const float*)d_in[2];
  const float* ppk    = (const float*)d_in[3];
  const float* ppv    = (const float*)d_in[4];
  const float* pk     = (const float*)d_in[5];
  const float* pv     = (const float*)d_in[6];
  const float* Wq     = (const float*)d_in[7];
  const float* bq     = (const float*)d_in[8];
  const float* Wk     = (const float*)d_in[9];
  const float* bk     = (const float*)d_in[10];
  const float* Wv     = (const float*)d_in[11];
  const float* bv     = (const float*)d_in[12];
  float* out = (float*)d_out;

  unsigned short* qws = (unsigned short*)d_ws;                 // 1 MB bf16 Q
  float* kws = (float*)((char*)d_ws + (1u << 20));             // 2 MB fp32 new K
  float* vws = (float*)((char*)d_ws + 3u * (1u << 20));        // 2 MB fp32 new V
  float* pctx = (float*)((char*)d_ws + 5u * (1u << 20));       // 8 MB partial ctx
  float* pml  = (float*)((char*)d_ws + 13u * (1u << 20));      // 256 KB partial m/l

  proj_kernel<<<dim3(8, 48), 256, 0, stream>>>(hidden, Wq, bq, Wk, bk, Wv, bv,
                                               qws, kws, vws);
  attn_kernel<<<dim3(512, NSPLIT), 256, 0, stream>>>(mask, rel, ppk, ppv, pk, pv,
                                                     qws, kws, vws, pctx, pml);
  merge_kernel<<<dim3(512), 256, 0, stream>>>(pctx, pml, out);
}